// Round 5
// baseline (270.044 us; speedup 1.0000x reference)
//
#include <hip/hip_runtime.h>

// Problem constants
#define N_ROWS   32768      // 64*512 flattened z rows
#define KCODES   1024
#define DDIM     256
#define RPB      64         // rows per argmin block: As=64KB -> 2 blocks/CU
#define NBLK     512        // 32768/64

// d_out float offsets (outputs concatenated in reference return order)
#define O_ZQ     0                    // 8388608
#define O_LOSS   8388608              // 1
#define O_IDX    8388609              // 32768
#define O_NCS    8421377              // 1024
#define O_NEA    8422401              // 262144
#define O_NEMB   8684545              // 262144

// workspace float offsets
#define W_CNT    262144               // 1024 ints (zeroed in k_prep2)
#define W_ENORM  263168               // 1024
#define W_LOSSP  264192               // 512
#define W_IDX    265792               // 32768 ints
// (W_ESUM / W_CUR / W_SORT / W_RANK retired in R5 — tail is gather-based)

typedef _Float16 half_t;
typedef __attribute__((ext_vector_type(8))) _Float16 half8;
typedef __attribute__((ext_vector_type(4))) float floatx4;

// ---------------------------------------------------------------------------
// Pack B into MFMA-native fragment order + compute ||e||^2.
// Layout (compact-addressing, R3): Bp[g16][pk][ns][lane][8]:
//   g16 = cq*4+g4 (wave-group, 16), pk = packed k-step (16: e_hi pk 0..7 +
//   e_lo pk 8..15), ns = 16-code subtile (4), lane (col=lane&15,
//   k=(lane>>4)*8+j). A wave-step's 4 ns loads span one contiguous 4KB
//   window -> single address reg + imm offsets in k_argmin.
// Block 0 also zeroes cnts.
__global__ __launch_bounds__(256)
void k_prep2(const float* __restrict__ emb, float* __restrict__ enorm,
             half_t* __restrict__ Bp, int* __restrict__ cnts) {
    __shared__ half_t hi[16 * 256];
    __shared__ half_t lo[16 * 256];
    __shared__ float  ssum[256];
    const int ct  = blockIdx.x;       // 16-code tile
    const int tid = threadIdx.x;
    const int c16 = tid >> 4;         // code within tile
    const int dp  = tid & 15;         // 16-dim part

    if (ct == 0) {                    // zero cnts: 1024 ints = 256 int4
        int4 zz = {0, 0, 0, 0};
        ((int4*)cnts)[tid] = zz;
    }

    float ss = 0.f;
    #pragma unroll
    for (int i = 0; i < 4; ++i) {
        float4 v = *(const float4*)(emb + (size_t)(ct * 16 + c16) * DDIM + dp * 16 + i * 4);
        ss += v.x * v.x + v.y * v.y + v.z * v.z + v.w * v.w;
        #pragma unroll
        for (int q = 0; q < 4; ++q) {
            float f = (&v.x)[q];
            half_t h = (half_t)f;
            hi[c16 * 256 + dp * 16 + i * 4 + q] = h;
            lo[c16 * 256 + dp * 16 + i * 4 + q] = (half_t)(f - (float)h);
        }
    }
    ssum[tid] = ss;
    __syncthreads();
    if (tid < 16) {
        float s = 0.f;
        #pragma unroll
        for (int i = 0; i < 16; ++i) s += ssum[tid * 16 + i];
        enorm[ct * 16 + tid] = s;
    }

    // write phase: 16 packed steps x 64 lanes x 8 halfs
    const int g16 = ((ct >> 4) << 2) | ((ct >> 2) & 3);
    const int ns  = ct & 3;
    #pragma unroll
    for (int i = 0; i < 4; ++i) {
        int f    = tid + i * 256;     // 0..1023
        int ks   = f >> 6;            // pk 0..15
        int lane = f & 63;
        int cc   = lane & 15;
        int seg  = ks >> 3;           // 0:hi 1:lo
        int ko   = (ks & 7) * 32 + (lane >> 4) * 8;
        const half_t* src = (seg == 1) ? lo : hi;
        half8 v = *(const half8*)(src + cc * 256 + ko);
        *(half8*)(Bp + (((size_t)(g16 * 16 + ks) * 4 + ns) * 64 + lane) * 8) = v;
    }
}

// ---------------------------------------------------------------------------
// MFMA argmin. dist(r,c)=||e||^2-2 z.e; fp16 hi/lo 3-term split:
// z.e ~= z_hi.e_hi + z_hi.e_lo + z_lo.e_hi.
// R5: PAIRED phases — e_hi tiles (pk 0..7) are loaded ONCE and MFMA'd
// twice (z_hi AND z_lo), cutting B L2 traffic 96->64KB per wave-group
// (was ~45us of pure L2 time at 1.6GB/dispatch; now ~1.05GB). 16 MFMA
// per paired load also doubles compute-per-load, so depth-2 ping-pong
// (~310 cyc cover) suffices; 16 super-steps, parity static via unroll 2.
// PLAIN __launch_bounds__(512) — NO min-waves arg, EVER (R5/R7/R8 of the
// prior session: the 2nd arg is a MINIMUM; the allocator overshoots ->
// 64-VGPR cap -> 1.2GB scratch spill).
__global__ __launch_bounds__(512)
void k_argmin(const float* __restrict__ z, const half_t* __restrict__ Bp,
              const float* __restrict__ enorm, const float* __restrict__ embf,
              int* __restrict__ out_idx, float* __restrict__ out_idx_f,
              float* __restrict__ out_zq, float* __restrict__ lossp,
              int* __restrict__ counts_i) {
    __shared__ __align__(16) half_t As[RPB * 512];   // 64 KB

    const int tid  = threadIdx.x;
    const int w    = tid >> 6;        // 0..7
    const int lane = tid & 63;
    const int tx   = lane & 15;
    const int quad = lane >> 4;
    const int rh   = w >> 2;          // row half: 0 -> rows 0..31, 1 -> 32..63
    const int cq   = w & 3;           // code quarter: codes [cq*256, cq*256+256)
    const int rbase = blockIdx.x * RPB;

    // ---- stage A: read z fp32, split hi/lo in-register, swizzled LDS store.
    {
        const int arow = w * 8 + (lane >> 3);   // 0..63, wave-local 8 rows
        const int sw   = arow & 7;
        #pragma unroll
        for (int it = 0; it < 4; ++it) {
            int g = it * 8 + (lane & 7);        // 0..31
            const float* zp = z + (size_t)(rbase + arow) * DDIM + g * 8;
            float4 v0 = *(const float4*)zp;
            float4 v1 = *(const float4*)(zp + 4);
            half8 hi, lo;
            hi[0] = (half_t)v0.x; lo[0] = (half_t)(v0.x - (float)hi[0]);
            hi[1] = (half_t)v0.y; lo[1] = (half_t)(v0.y - (float)hi[1]);
            hi[2] = (half_t)v0.z; lo[2] = (half_t)(v0.z - (float)hi[2]);
            hi[3] = (half_t)v0.w; lo[3] = (half_t)(v0.w - (float)hi[3]);
            hi[4] = (half_t)v1.x; lo[4] = (half_t)(v1.x - (float)hi[4]);
            hi[5] = (half_t)v1.y; lo[5] = (half_t)(v1.y - (float)hi[5]);
            hi[6] = (half_t)v1.z; lo[6] = (half_t)(v1.z - (float)hi[6]);
            hi[7] = (half_t)v1.w; lo[7] = (half_t)(v1.w - (float)hi[7]);
            *(half8*)(&As[arow * 512 + ((g ^ sw)) * 8])        = hi;  // k8 = g
            *(half8*)(&As[arow * 512 + (((32 + g) ^ sw)) * 8]) = lo;  // k8 = 32+g
        }
    }
    __syncthreads();                  // the ONLY main-loop barrier

    floatx4 zero4 = {0.f, 0.f, 0.f, 0.f};
    float bd[2][4];
    int   bi[2][4];
    #pragma unroll
    for (int mt = 0; mt < 2; ++mt)
        #pragma unroll
        for (int r = 0; r < 4; ++r) { bd[mt][r] = 3.402823466e38f; bi[mt][r] = 0; }

    for (int g4 = 0; g4 < 4; ++g4) {
        const int cb = cq * 256 + g4 * 64;
        const half_t* Bg = Bp + (size_t)(cq * 4 + g4) * 32768 + (size_t)lane * 8;

        floatx4 acc[2][4];
        #pragma unroll
        for (int mt = 0; mt < 2; ++mt)
            #pragma unroll
            for (int ns = 0; ns < 4; ++ns) acc[mt][ns] = zero4;

        half8 B0[4], B1[4];
        #define LOADB(PK, BUF)                                                 \
            { const half_t* bp_ = Bg + (PK) * 2048;                            \
              _Pragma("unroll")                                                \
              for (int ns = 0; ns < 4; ++ns)                                   \
                  BUF[ns] = *(const half8*)(bp_ + ns * 512); }
        #define MFMA_BLK(AF, BUF)                                              \
            _Pragma("unroll")                                                  \
            for (int mt = 0; mt < 2; ++mt)                                     \
                _Pragma("unroll")                                              \
                for (int ns = 0; ns < 4; ++ns)                                 \
                    acc[mt][ns] = __builtin_amdgcn_mfma_f32_16x16x32_f16(      \
                        AF[mt], BUF[ns], acc[mt][ns], 0, 0, 0);

        LOADB(0, B0);
        LOADB(1, B1);

        // super-steps 0..7: B = e_hi pk s, used TWICE (z_hi & z_lo)
        #pragma unroll 2
        for (int s = 0; s < 8; ++s) {
            half8 a0[2], a1[2];
            #pragma unroll
            for (int mt = 0; mt < 2; ++mt) {
                int row = rh * 32 + mt * 16 + tx;
                int sw  = row & 7;
                a0[mt] = *(half8*)(&As[row * 512 + ((s * 4 + quad) ^ sw) * 8]);
                a1[mt] = *(half8*)(&As[row * 512 + ((32 + s * 4 + quad) ^ sw) * 8]);
            }
            if (s & 1) { MFMA_BLK(a0, B1) MFMA_BLK(a1, B1) LOADB(s + 2, B1); }
            else       { MFMA_BLK(a0, B0) MFMA_BLK(a1, B0) LOADB(s + 2, B0); }
        }
        // super-steps 8..15: B = e_lo pk s, used once (z_hi)
        #pragma unroll 2
        for (int s = 8; s < 16; ++s) {
            half8 a0[2];
            #pragma unroll
            for (int mt = 0; mt < 2; ++mt) {
                int row = rh * 32 + mt * 16 + tx;
                int sw  = row & 7;
                a0[mt] = *(half8*)(&As[row * 512 + (((s - 8) * 4 + quad) ^ sw) * 8]);
            }
            if (s & 1) { MFMA_BLK(a0, B1) if (s + 2 < 16) LOADB(s + 2, B1); }
            else       { MFMA_BLK(a0, B0) if (s + 2 < 16) LOADB(s + 2, B0); }
        }
        #undef LOADB
        #undef MFMA_BLK

        // fold group into running argmin (codes ascending; strict <, min-index)
        #pragma unroll
        for (int ns = 0; ns < 4; ++ns) {
            float en = enorm[cb + ns * 16 + tx];
            int   cc = cb + ns * 16 + tx;
            #pragma unroll
            for (int mt = 0; mt < 2; ++mt)
                #pragma unroll
                for (int r = 0; r < 4; ++r) {
                    float d = fmaf(-2.f, acc[mt][ns][r], en);
                    if (d < bd[mt][r]) { bd[mt][r] = d; bi[mt][r] = cc; }
                }
        }
    }

    // reduce across 16 tx lanes (same row, different codes); ties -> min index
    #pragma unroll
    for (int mt = 0; mt < 2; ++mt)
        #pragma unroll
        for (int r = 0; r < 4; ++r) {
            float d = bd[mt][r];
            int   b = bi[mt][r];
            #pragma unroll
            for (int off = 8; off > 0; off >>= 1) {
                float od = __shfl_xor(d, off);
                int   ob = __shfl_xor(b, off);
                if (od < d || (od == d && ob < b)) { d = od; b = ob; }
            }
            bd[mt][r] = d; bi[mt][r] = b;
        }

    // cross-wave reduce via LDS (reuse As): per row, 4 code-quarter candidates
    __syncthreads();
    float* sd   = (float*)As;          // [64 rows][4 quarters]
    int*   si   = ((int*)As) + 256;
    int*   sidx = ((int*)As) + 512;    // final idx per row
    if (tx == 0) {
        #pragma unroll
        for (int mt = 0; mt < 2; ++mt)
            #pragma unroll
            for (int r = 0; r < 4; ++r) {
                int row = rh * 32 + mt * 16 + quad * 4 + r;  // C-layout: row = quad*4+reg
                sd[row * 4 + cq] = bd[mt][r];
                si[row * 4 + cq] = bi[mt][r];
            }
    }
    __syncthreads();
    if (tid < RPB) {
        int row = tid;
        float d = sd[row * 4];
        int   b = si[row * 4];
        #pragma unroll
        for (int ww = 1; ww < 4; ++ww) {
            float od = sd[row * 4 + ww];
            int   ob = si[row * 4 + ww];
            if (od < d || (od == d && ob < b)) { d = od; b = ob; }
        }
        sidx[row] = b;
        out_idx[rbase + row]   = b;
        out_idx_f[rbase + row] = (float)b;
        atomicAdd(&counts_i[b], 1);
    }
    __syncthreads();

    // ---- fused z_q epilogue: z_q_st write + commitment-loss partial
    float l = 0.f;
    #pragma unroll
    for (int u = 0; u < 8; ++u) {
        int gi  = tid + u * 512;       // 0..4095 float4s = 64 rows x 64
        int row = gi >> 6;
        int c4  = gi & 63;
        int k   = sidx[row];           // wave-uniform
        float4 zv = *(const float4*)(z    + (size_t)(rbase + row) * DDIM + c4 * 4);
        float4 ev = *(const float4*)(embf + (size_t)k * DDIM + c4 * 4);
        float dx = ev.x - zv.x, dy = ev.y - zv.y, dz = ev.z - zv.z, dw = ev.w - zv.w;
        float4 o = { zv.x + dx, zv.y + dy, zv.z + dz, zv.w + dw };  // z + (z_q - z)
        *(float4*)(out_zq + (size_t)(rbase + row) * DDIM + c4 * 4) = o;
        l += dx * dx + dy * dy + dz * dz + dw * dw;
    }
    #pragma unroll
    for (int off = 32; off > 0; off >>= 1) l += __shfl_down(l, off);
    __shared__ float ls[8];
    if (lane == 0) ls[w] = l;
    __syncthreads();
    if (tid == 0) {
        float s = 0.f;
        #pragma unroll
        for (int i = 0; i < 8; ++i) s += ls[i];
        lossp[blockIdx.x] = s;
    }
}

// ---------------------------------------------------------------------------
// R5 gather-tail: ONE kernel replaces scan/rank/esum/embed (no sort, no
// global atomics, no cooperative launch — R4 proved grid.sync costs more
// than the boundaries it removes). 256 blocks x 4 codes each: scan
// idx[32768] (L2-resident), build per-chunk LDS row lists, gather matching
// z rows (each z row read exactly once chip-wide), accumulate esum in
// registers, apply embed update. n/ncs recomputed redundantly per block.
__global__ __launch_bounds__(256)
void k_tail2(const float* __restrict__ cs_in, const int* __restrict__ counts_i,
             const float* __restrict__ lossp, const int* __restrict__ idx,
             const float* __restrict__ z, const float* __restrict__ ea,
             float* __restrict__ out_ncs, float* __restrict__ loss_out,
             float* __restrict__ out_nea, float* __restrict__ out_nemb) {
    const int tid  = threadIdx.x;
    const int bid  = blockIdx.x;
    const int kb   = bid * 4;         // this block's 4 codes
    const int w    = tid >> 6;
    const int lane = tid & 63;

    __shared__ int    list[4096];     // worst case: whole chunk matches
    __shared__ int    lcnt;
    __shared__ float4 accW[4][4][64]; // [code][wave][lane] partial esums
    __shared__ float  snv[4], slv[4];

    // ---- n (and block 0: ncs + loss) from counts/cs_in, redundant per block
    float pn = 0.f;
    #pragma unroll
    for (int i = 0; i < 4; ++i) {
        int c = tid * 4 + i;
        float nc = cs_in[c] * 0.99f + 0.01f * (float)counts_i[c];
        pn += nc;
        if (bid == 0) out_ncs[c] = nc;
    }
    float pl = (bid == 0) ? (lossp[tid] + lossp[tid + 256]) : 0.f;
    #pragma unroll
    for (int off = 32; off > 0; off >>= 1) {
        pn += __shfl_down(pn, off);
        pl += __shfl_down(pl, off);
    }
    if (lane == 0) { snv[w] = pn; slv[w] = pl; }
    __syncthreads();
    const float nval = snv[0] + snv[1] + snv[2] + snv[3];
    if (bid == 0 && tid == 0)
        loss_out[0] = 0.25f * ((slv[0] + slv[1] + slv[2] + slv[3]) / 8388608.0f);

    // ---- scan idx in 8 chunks of 4096, gather + accumulate
    float4 a0 = {0.f,0.f,0.f,0.f}, a1 = a0, a2 = a0, a3 = a0;
    for (int ch = 0; ch < 8; ++ch) {
        __syncthreads();               // prior chunk's list reads done
        if (tid == 0) lcnt = 0;
        __syncthreads();
        const int4* ip = (const int4*)(idx + ch * 4096);
        #pragma unroll
        for (int i = 0; i < 4; ++i) {
            int4 v = ip[tid + i * 256];
            int r0 = ch * 4096 + (tid + i * 256) * 4;
            int d;
            d = v.x - kb; if ((unsigned)d < 4u) { int p = atomicAdd(&lcnt, 1); list[p] = r0 | (d << 15); }
            d = v.y - kb; if ((unsigned)d < 4u) { int p = atomicAdd(&lcnt, 1); list[p] = (r0 + 1) | (d << 15); }
            d = v.z - kb; if ((unsigned)d < 4u) { int p = atomicAdd(&lcnt, 1); list[p] = (r0 + 2) | (d << 15); }
            d = v.w - kb; if ((unsigned)d < 4u) { int p = atomicAdd(&lcnt, 1); list[p] = (r0 + 3) | (d << 15); }
        }
        __syncthreads();
        const int n = lcnt;
        // wave-parallel: wave w takes entries w, w+4, ... (uniform in-wave)
        for (int i = w; i < n; i += 4) {
            int packed = list[i];
            int row = packed & 32767;
            int lc  = packed >> 15;    // wave-uniform branch
            float4 v = *((const float4*)(z + (size_t)row * DDIM) + lane);
            if      (lc == 0) { a0.x += v.x; a0.y += v.y; a0.z += v.z; a0.w += v.w; }
            else if (lc == 1) { a1.x += v.x; a1.y += v.y; a1.z += v.z; a1.w += v.w; }
            else if (lc == 2) { a2.x += v.x; a2.y += v.y; a2.z += v.z; a2.w += v.w; }
            else              { a3.x += v.x; a3.y += v.y; a3.z += v.z; a3.w += v.w; }
        }
    }
    __syncthreads();
    accW[0][w][lane] = a0;
    accW[1][w][lane] = a1;
    accW[2][w][lane] = a2;
    accW[3][w][lane] = a3;
    __syncthreads();

    // ---- embed: thread t -> code kb + (t>>6), dims (t&63)*4 .. +3
    {
        const int c = tid >> 6;
        const int l = tid & 63;
        float4 e0 = accW[c][0][l];
        float4 e1 = accW[c][1][l];
        float4 e2 = accW[c][2][l];
        float4 e3 = accW[c][3][l];
        float ex = e0.x + e1.x + e2.x + e3.x;
        float ey = e0.y + e1.y + e2.y + e3.y;
        float ez = e0.z + e1.z + e2.z + e3.z;
        float ew = e0.w + e1.w + e2.w + e3.w;
        size_t off = (size_t)(kb + c) * DDIM + l * 4;
        float4 av = *(const float4*)(ea + off);
        float4 nea = { av.x * 0.99f + 0.01f * ex,
                       av.y * 0.99f + 0.01f * ey,
                       av.z * 0.99f + 0.01f * ez,
                       av.w * 0.99f + 0.01f * ew };
        *(float4*)(out_nea + off) = nea;
        float ncv = cs_in[kb + c] * 0.99f + 0.01f * (float)counts_i[kb + c];
        float csv = (ncv + 1e-6f) / (nval + 0.001024f);   // (ncs+eps)/(n+K*eps)
        float4 nemb = { nea.x / csv, nea.y / csv, nea.z / csv, nea.w / csv };
        *(float4*)(out_nemb + off) = nemb;
    }
}

// ---------------------------------------------------------------------------
extern "C" void kernel_launch(void* const* d_in, const int* in_sizes, int n_in,
                              void* d_out, int out_size, void* d_ws, size_t ws_size,
                              hipStream_t stream) {
    const float* z   = (const float*)d_in[0];
    const float* emb = (const float*)d_in[1];
    const float* cs  = (const float*)d_in[2];
    const float* ea  = (const float*)d_in[3];
    float* out = (float*)d_out;
    float* ws  = (float*)d_ws;

    int*   cnts    = (int*)(ws + W_CNT);
    float* enorm   = ws + W_ENORM;
    float* lossp   = ws + W_LOSSP;
    int*   widx    = (int*)(ws + W_IDX);

    // packed-B fp16 scratch in dead O_NEA output region (16B-aligned;
    // k_tail2, the only writer of that region, runs last). 1MB.
    half_t* Bp = (half_t*)(out + O_NEA + 3);   // 524288 halfs

    k_prep2  <<<64, 256, 0, stream>>>(emb, enorm, Bp, cnts);
    k_argmin <<<NBLK, 512, 0, stream>>>(z, Bp, enorm, emb,
                                        widx, out + O_IDX, out + O_ZQ, lossp,
                                        cnts);
    k_tail2  <<<256, 256, 0, stream>>>(cs, cnts, lossp, widx, z, ea,
                                       out + O_NCS, out + O_LOSS,
                                       out + O_NEA, out + O_NEMB);
}

// Round 7
// 179.770 us; speedup vs baseline: 1.5022x; 1.5022x over previous
//
#include <hip/hip_runtime.h>

// Problem constants
#define N_ROWS   32768      // 64*512 flattened z rows
#define KCODES   1024
#define DDIM     256
#define RPB      64         // rows per argmin block: As=64KB -> 2 blocks/CU
#define NBLK     512        // 32768/64

// d_out float offsets (outputs concatenated in reference return order)
#define O_ZQ     0                    // 8388608
#define O_LOSS   8388608              // 1
#define O_IDX    8388609              // 32768
#define O_NCS    8421377              // 1024
#define O_NEA    8422401              // 262144
#define O_NEMB   8684545              // 262144

// workspace float offsets
#define W_ESUM   0                    // 262144 (zeroed in k_prep2)
#define W_CNT    262144               // 1024 ints (zeroed in k_prep2)
#define W_ENORM  263168               // 1024
#define W_LOSSP  264192               // 512
#define W_N      265728               // 1
#define W_IDX    265792               // 32768 ints
#define W_SORT   298560               // 32768 ints
#define W_RANK   331328               // 32768 ints (row's rank within its code)

typedef _Float16 half_t;
typedef __attribute__((ext_vector_type(8))) _Float16 half8;
typedef __attribute__((ext_vector_type(4))) float floatx4;

// ---------------------------------------------------------------------------
// Pack B into MFMA-native fragment order + compute ||e||^2.
// Layout (compact-addressing): Bp[g16][pk][ns][lane][8]:
//   g16 = cq*4+g4 (wave-group, 16), pk = packed k-step (16: e_hi pk 0..7 +
//   e_lo pk 8..15), ns = 16-code subtile (4), lane (col=lane&15,
//   k=(lane>>4)*8+j). A wave-step's 4 ns loads span one contiguous 4KB
//   window -> single address reg + imm offsets in k_argmin.
// Also zeroes esum (1MB) + cnts (4KB): 65792 float4 over 16384 threads.
__global__ __launch_bounds__(256)
void k_prep2(const float* __restrict__ emb, float* __restrict__ enorm,
             half_t* __restrict__ Bp, float* __restrict__ zero_ws) {
    __shared__ half_t hi[16 * 256];
    __shared__ half_t lo[16 * 256];
    __shared__ float  ssum[256];
    const int ct  = blockIdx.x;       // 16-code tile
    const int tid = threadIdx.x;
    const int c16 = tid >> 4;         // code within tile
    const int dp  = tid & 15;         // 16-dim part

    {   // zero esum + cnts (skew-proof tail needs esum=0: atomic run-flushes)
        float4 z4 = {0.f, 0.f, 0.f, 0.f};
        float4* wsf4 = (float4*)zero_ws;
        int t = ct * 256 + tid;
        #pragma unroll
        for (int i = 0; i < 4; ++i) wsf4[t + i * 16384] = z4;
        if (t < 256) wsf4[65536 + t] = z4;
    }

    float ss = 0.f;
    #pragma unroll
    for (int i = 0; i < 4; ++i) {
        float4 v = *(const float4*)(emb + (size_t)(ct * 16 + c16) * DDIM + dp * 16 + i * 4);
        ss += v.x * v.x + v.y * v.y + v.z * v.z + v.w * v.w;
        #pragma unroll
        for (int q = 0; q < 4; ++q) {
            float f = (&v.x)[q];
            half_t h = (half_t)f;
            hi[c16 * 256 + dp * 16 + i * 4 + q] = h;
            lo[c16 * 256 + dp * 16 + i * 4 + q] = (half_t)(f - (float)h);
        }
    }
    ssum[tid] = ss;
    __syncthreads();
    if (tid < 16) {
        float s = 0.f;
        #pragma unroll
        for (int i = 0; i < 16; ++i) s += ssum[tid * 16 + i];
        enorm[ct * 16 + tid] = s;
    }

    // write phase: 16 packed steps x 64 lanes x 8 halfs
    const int g16 = ((ct >> 4) << 2) | ((ct >> 2) & 3);
    const int ns  = ct & 3;
    #pragma unroll
    for (int i = 0; i < 4; ++i) {
        int f    = tid + i * 256;     // 0..1023
        int ks   = f >> 6;            // pk 0..15
        int lane = f & 63;
        int cc   = lane & 15;
        int seg  = ks >> 3;           // 0:hi 1:lo
        int ko   = (ks & 7) * 32 + (lane >> 4) * 8;
        const half_t* src = (seg == 1) ? lo : hi;
        half8 v = *(const half8*)(src + cc * 256 + ko);
        *(half8*)(Bp + (((size_t)(g16 * 16 + ks) * 4 + ns) * 64 + lane) * 8) = v;
    }
}

// ---------------------------------------------------------------------------
// MFMA argmin. dist(r,c)=||e||^2-2 z.e; fp16 hi/lo 3-term split:
// z.e ~= z_hi.e_hi + z_hi.e_lo + z_lo.e_hi.
// Paired phases (R5): e_hi tiles (pk 0..7) loaded ONCE, MFMA'd twice
// (z_hi & z_lo) — 16 loads instead of 24 per wave-group (-33% L2 traffic).
// Emits rank_ws[row] = atomicAdd(counts[code]) so the tail sort needs no
// second atomic pass.
// PLAIN __launch_bounds__(512) — NO min-waves arg, EVER (prior R5/R7/R8:
// the 2nd arg is a MINIMUM; allocator overshoots -> 64-VGPR cap -> spill).
__global__ __launch_bounds__(512)
void k_argmin(const float* __restrict__ z, const half_t* __restrict__ Bp,
              const float* __restrict__ enorm, const float* __restrict__ embf,
              int* __restrict__ out_idx, float* __restrict__ out_idx_f,
              float* __restrict__ out_zq, float* __restrict__ lossp,
              int* __restrict__ counts_i, int* __restrict__ rank_ws) {
    __shared__ __align__(16) half_t As[RPB * 512];   // 64 KB

    const int tid  = threadIdx.x;
    const int w    = tid >> 6;        // 0..7
    const int lane = tid & 63;
    const int tx   = lane & 15;
    const int quad = lane >> 4;
    const int rh   = w >> 2;          // row half: 0 -> rows 0..31, 1 -> 32..63
    const int cq   = w & 3;           // code quarter: codes [cq*256, cq*256+256)
    const int rbase = blockIdx.x * RPB;

    // ---- stage A: read z fp32, split hi/lo in-register, swizzled LDS store.
    {
        const int arow = w * 8 + (lane >> 3);   // 0..63, wave-local 8 rows
        const int sw   = arow & 7;
        #pragma unroll
        for (int it = 0; it < 4; ++it) {
            int g = it * 8 + (lane & 7);        // 0..31
            const float* zp = z + (size_t)(rbase + arow) * DDIM + g * 8;
            float4 v0 = *(const float4*)zp;
            float4 v1 = *(const float4*)(zp + 4);
            half8 hi, lo;
            hi[0] = (half_t)v0.x; lo[0] = (half_t)(v0.x - (float)hi[0]);
            hi[1] = (half_t)v0.y; lo[1] = (half_t)(v0.y - (float)hi[1]);
            hi[2] = (half_t)v0.z; lo[2] = (half_t)(v0.z - (float)hi[2]);
            hi[3] = (half_t)v0.w; lo[3] = (half_t)(v0.w - (float)hi[3]);
            hi[4] = (half_t)v1.x; lo[4] = (half_t)(v1.x - (float)hi[4]);
            hi[5] = (half_t)v1.y; lo[5] = (half_t)(v1.y - (float)hi[5]);
            hi[6] = (half_t)v1.z; lo[6] = (half_t)(v1.z - (float)hi[6]);
            hi[7] = (half_t)v1.w; lo[7] = (half_t)(v1.w - (float)hi[7]);
            *(half8*)(&As[arow * 512 + ((g ^ sw)) * 8])        = hi;  // k8 = g
            *(half8*)(&As[arow * 512 + (((32 + g) ^ sw)) * 8]) = lo;  // k8 = 32+g
        }
    }
    __syncthreads();                  // the ONLY main-loop barrier

    floatx4 zero4 = {0.f, 0.f, 0.f, 0.f};
    float bd[2][4];
    int   bi[2][4];
    #pragma unroll
    for (int mt = 0; mt < 2; ++mt)
        #pragma unroll
        for (int r = 0; r < 4; ++r) { bd[mt][r] = 3.402823466e38f; bi[mt][r] = 0; }

    for (int g4 = 0; g4 < 4; ++g4) {
        const int cb = cq * 256 + g4 * 64;
        const half_t* Bg = Bp + (size_t)(cq * 4 + g4) * 32768 + (size_t)lane * 8;

        floatx4 acc[2][4];
        #pragma unroll
        for (int mt = 0; mt < 2; ++mt)
            #pragma unroll
            for (int ns = 0; ns < 4; ++ns) acc[mt][ns] = zero4;

        half8 B0[4], B1[4];
        #define LOADB(PK, BUF)                                                 \
            { const half_t* bp_ = Bg + (PK) * 2048;                            \
              _Pragma("unroll")                                                \
              for (int ns = 0; ns < 4; ++ns)                                   \
                  BUF[ns] = *(const half8*)(bp_ + ns * 512); }
        #define MFMA_BLK(AF, BUF)                                              \
            _Pragma("unroll")                                                  \
            for (int mt = 0; mt < 2; ++mt)                                     \
                _Pragma("unroll")                                              \
                for (int ns = 0; ns < 4; ++ns)                                 \
                    acc[mt][ns] = __builtin_amdgcn_mfma_f32_16x16x32_f16(      \
                        AF[mt], BUF[ns], acc[mt][ns], 0, 0, 0);

        LOADB(0, B0);
        LOADB(1, B1);

        // super-steps 0..7: B = e_hi pk s, used TWICE (z_hi & z_lo)
        #pragma unroll 2
        for (int s = 0; s < 8; ++s) {
            half8 a0[2], a1[2];
            #pragma unroll
            for (int mt = 0; mt < 2; ++mt) {
                int row = rh * 32 + mt * 16 + tx;
                int sw  = row & 7;
                a0[mt] = *(half8*)(&As[row * 512 + ((s * 4 + quad) ^ sw) * 8]);
                a1[mt] = *(half8*)(&As[row * 512 + ((32 + s * 4 + quad) ^ sw) * 8]);
            }
            if (s & 1) { MFMA_BLK(a0, B1) MFMA_BLK(a1, B1) LOADB(s + 2, B1); }
            else       { MFMA_BLK(a0, B0) MFMA_BLK(a1, B0) LOADB(s + 2, B0); }
        }
        // super-steps 8..15: B = e_lo pk s, used once (z_hi)
        #pragma unroll 2
        for (int s = 8; s < 16; ++s) {
            half8 a0[2];
            #pragma unroll
            for (int mt = 0; mt < 2; ++mt) {
                int row = rh * 32 + mt * 16 + tx;
                int sw  = row & 7;
                a0[mt] = *(half8*)(&As[row * 512 + (((s - 8) * 4 + quad) ^ sw) * 8]);
            }
            if (s & 1) { MFMA_BLK(a0, B1) if (s + 2 < 16) LOADB(s + 2, B1); }
            else       { MFMA_BLK(a0, B0) if (s + 2 < 16) LOADB(s + 2, B0); }
        }
        #undef LOADB
        #undef MFMA_BLK

        // fold group into running argmin (codes ascending; strict <, min-index)
        #pragma unroll
        for (int ns = 0; ns < 4; ++ns) {
            float en = enorm[cb + ns * 16 + tx];
            int   cc = cb + ns * 16 + tx;
            #pragma unroll
            for (int mt = 0; mt < 2; ++mt)
                #pragma unroll
                for (int r = 0; r < 4; ++r) {
                    float d = fmaf(-2.f, acc[mt][ns][r], en);
                    if (d < bd[mt][r]) { bd[mt][r] = d; bi[mt][r] = cc; }
                }
        }
    }

    // reduce across 16 tx lanes (same row, different codes); ties -> min index
    #pragma unroll
    for (int mt = 0; mt < 2; ++mt)
        #pragma unroll
        for (int r = 0; r < 4; ++r) {
            float d = bd[mt][r];
            int   b = bi[mt][r];
            #pragma unroll
            for (int off = 8; off > 0; off >>= 1) {
                float od = __shfl_xor(d, off);
                int   ob = __shfl_xor(b, off);
                if (od < d || (od == d && ob < b)) { d = od; b = ob; }
            }
            bd[mt][r] = d; bi[mt][r] = b;
        }

    // cross-wave reduce via LDS (reuse As): per row, 4 code-quarter candidates
    __syncthreads();
    float* sd   = (float*)As;          // [64 rows][4 quarters]
    int*   si   = ((int*)As) + 256;
    int*   sidx = ((int*)As) + 512;    // final idx per row
    if (tx == 0) {
        #pragma unroll
        for (int mt = 0; mt < 2; ++mt)
            #pragma unroll
            for (int r = 0; r < 4; ++r) {
                int row = rh * 32 + mt * 16 + quad * 4 + r;  // C-layout: row = quad*4+reg
                sd[row * 4 + cq] = bd[mt][r];
                si[row * 4 + cq] = bi[mt][r];
            }
    }
    __syncthreads();
    if (tid < RPB) {
        int row = tid;
        float d = sd[row * 4];
        int   b = si[row * 4];
        #pragma unroll
        for (int ww = 1; ww < 4; ++ww) {
            float od = sd[row * 4 + ww];
            int   ob = si[row * 4 + ww];
            if (od < d || (od == d && ob < b)) { d = od; b = ob; }
        }
        sidx[row] = b;
        out_idx[rbase + row]   = b;
        out_idx_f[rbase + row] = (float)b;
        int rk = atomicAdd(&counts_i[b], 1);   // rank of this row within code b
        rank_ws[rbase + row] = rk;
    }
    __syncthreads();

    // ---- fused z_q epilogue: z_q_st write + commitment-loss partial
    float l = 0.f;
    #pragma unroll
    for (int u = 0; u < 8; ++u) {
        int gi  = tid + u * 512;       // 0..4095 float4s = 64 rows x 64
        int row = gi >> 6;
        int c4  = gi & 63;
        int k   = sidx[row];           // wave-uniform
        float4 zv = *(const float4*)(z    + (size_t)(rbase + row) * DDIM + c4 * 4);
        float4 ev = *(const float4*)(embf + (size_t)k * DDIM + c4 * 4);
        float dx = ev.x - zv.x, dy = ev.y - zv.y, dz = ev.z - zv.z, dw = ev.w - zv.w;
        float4 o = { zv.x + dx, zv.y + dy, zv.z + dz, zv.w + dw };  // z + (z_q - z)
        *(float4*)(out_zq + (size_t)(rbase + row) * DDIM + c4 * 4) = o;
        l += dx * dx + dy * dy + dz * dz + dw * dw;
    }
    #pragma unroll
    for (int off = 32; off > 0; off >>= 1) l += __shfl_down(l, off);
    __shared__ float ls[8];
    if (lane == 0) ls[w] = l;
    __syncthreads();
    if (tid == 0) {
        float s = 0.f;
        #pragma unroll
        for (int i = 0; i < 8; ++i) s += ls[i];
        lossp[blockIdx.x] = s;
    }
}

// ---------------------------------------------------------------------------
// Fused scan+rank (replaces R3's k_scan + k_rank, saves one boundary):
// every block redundantly LDS-scans counts[1024] (~2us), then scatters its
// 256-row slice atomic-free: rows_sorted[base[k] + rank[r]] = r. Row-sliced
// -> skew-proof (R5 lesson: NOTHING in the tail may scale with per-code
// population). Block 0 additionally emits ncs / n / loss.
__global__ __launch_bounds__(256)
void k_scatter(const float* __restrict__ cs_in, const int* __restrict__ counts_i,
               const float* __restrict__ lossp, const int* __restrict__ idx,
               const int* __restrict__ rank_ws, int* __restrict__ rows_sorted,
               float* __restrict__ out_ncs, float* __restrict__ n_ws,
               float* __restrict__ loss_out) {
    const int tid = threadIdx.x;
    const int bid = blockIdx.x;       // 128 blocks x 256 rows
    __shared__ int ps[256];
    __shared__ int base_s[1024];
    __shared__ float sv[4], sl[4];

    int c[4]; int pt = 0;
    #pragma unroll
    for (int i = 0; i < 4; ++i) { c[i] = counts_i[tid * 4 + i]; pt += c[i]; }
    ps[tid] = pt;
    __syncthreads();
    for (int s = 1; s < 256; s <<= 1) {
        int v = (tid >= s) ? ps[tid - s] : 0;
        __syncthreads();
        ps[tid] += v;
        __syncthreads();
    }
    int o = ps[tid] - pt;              // exclusive base for this thread's 4 bins
    float v = 0.f;
    #pragma unroll
    for (int i = 0; i < 4; ++i) {
        base_s[tid * 4 + i] = o;
        o += c[i];
        if (bid == 0) {
            float nc = cs_in[tid * 4 + i] * 0.99f + 0.01f * (float)c[i];
            out_ncs[tid * 4 + i] = nc;
            v += nc;
        }
    }
    if (bid == 0) {
        float l = lossp[tid] + lossp[tid + 256];
        #pragma unroll
        for (int off = 32; off > 0; off >>= 1) {
            v += __shfl_down(v, off);
            l += __shfl_down(l, off);
        }
        if ((tid & 63) == 0) { sv[tid >> 6] = v; sl[tid >> 6] = l; }
    }
    __syncthreads();                   // base_s (and sv/sl) ready
    if (bid == 0 && tid == 0) {
        n_ws[0]     = sv[0] + sv[1] + sv[2] + sv[3];
        loss_out[0] = 0.25f * ((sl[0] + sl[1] + sl[2] + sl[3]) / 8388608.0f);
    }
    int r = bid * 256 + tid;
    int k = idx[r];
    rows_sorted[base_s[k] + rank_ws[r]] = r;
}

// ---------------------------------------------------------------------------
// Skew-proof segment-sum (R3-proven): each wave owns exactly 32 sorted
// positions, accumulates equal-code runs in registers, flushes runs via
// fp32 atomics. Position-sliced -> perfectly balanced under any skew.
__global__ __launch_bounds__(256)
void k_esum2(const float* __restrict__ z, const int* __restrict__ rows_sorted,
             const int* __restrict__ idx, float* __restrict__ esum) {
    const int tid  = threadIdx.x;
    const int w    = tid >> 6;        // 0..3
    const int lane = tid & 63;
    const int base = (blockIdx.x * 4 + w) * 32;   // 256 blocks x 4 waves x 32

    int r = rows_sorted[base + (lane & 31)];
    int c = idx[r];
    float4 acc = {0.f, 0.f, 0.f, 0.f};
    #pragma unroll 8
    for (int j = 0; j < 32; ++j) {
        int rj = __shfl(r, j);
        int cj = __shfl(c, j);
        float4 zv = *(const float4*)(z + (size_t)rj * DDIM + lane * 4);
        acc.x += zv.x; acc.y += zv.y; acc.z += zv.z; acc.w += zv.w;
        int cn = (j < 31) ? __shfl(c, j + 1) : -1;
        if (cn != cj) {                // wave-uniform branch
            float* p = esum + (size_t)cj * DDIM + lane * 4;
            atomicAdd(p + 0, acc.x);
            atomicAdd(p + 1, acc.y);
            atomicAdd(p + 2, acc.z);
            atomicAdd(p + 3, acc.w);
            acc.x = 0.f; acc.y = 0.f; acc.z = 0.f; acc.w = 0.f;
        }
    }
}

// ---------------------------------------------------------------------------
// Embed: 256 blocks x 4 codes; thread t -> code kb+(t>>6), dims (t&63)*4.
__global__ __launch_bounds__(256)
void k_embed(const float* __restrict__ ea, const float* __restrict__ esum,
             const float* __restrict__ ncs, const float* __restrict__ n_ws,
             float* __restrict__ out_nea, float* __restrict__ out_nemb) {
    const int tid = threadIdx.x;
    const int kb  = blockIdx.x * 4;
    const int c   = tid >> 6;
    const int l   = tid & 63;
    size_t off = (size_t)(kb + c) * DDIM + l * 4;
    float4 av = *(const float4*)(ea   + off);
    float4 ev = *(const float4*)(esum + off);
    float4 nea = { av.x * 0.99f + 0.01f * ev.x,
                   av.y * 0.99f + 0.01f * ev.y,
                   av.z * 0.99f + 0.01f * ev.z,
                   av.w * 0.99f + 0.01f * ev.w };
    *(float4*)(out_nea + off) = nea;
    float csv = (ncs[kb + c] + 1e-6f) / (n_ws[0] + 0.001024f);  // (ncs+eps)/(n+K*eps)
    float4 nemb = { nea.x / csv, nea.y / csv, nea.z / csv, nea.w / csv };
    *(float4*)(out_nemb + off) = nemb;
}

// ---------------------------------------------------------------------------
extern "C" void kernel_launch(void* const* d_in, const int* in_sizes, int n_in,
                              void* d_out, int out_size, void* d_ws, size_t ws_size,
                              hipStream_t stream) {
    const float* z   = (const float*)d_in[0];
    const float* emb = (const float*)d_in[1];
    const float* cs  = (const float*)d_in[2];
    const float* ea  = (const float*)d_in[3];
    float* out = (float*)d_out;
    float* ws  = (float*)d_ws;

    float* esum    = ws + W_ESUM;
    int*   cnts    = (int*)(ws + W_CNT);
    float* enorm   = ws + W_ENORM;
    float* lossp   = ws + W_LOSSP;
    float* wn      = ws + W_N;
    int*   widx    = (int*)(ws + W_IDX);
    int*   rsorted = (int*)(ws + W_SORT);
    int*   rankw   = (int*)(ws + W_RANK);

    // packed-B fp16 scratch in dead O_NEA output region (16B-aligned;
    // k_embed, the only writer of that region, runs last). 1MB.
    half_t* Bp = (half_t*)(out + O_NEA + 3);   // 524288 halfs

    k_prep2   <<<64, 256, 0, stream>>>(emb, enorm, Bp, ws);
    k_argmin  <<<NBLK, 512, 0, stream>>>(z, Bp, enorm, emb,
                                         widx, out + O_IDX, out + O_ZQ, lossp,
                                         cnts, rankw);
    k_scatter <<<128, 256, 0, stream>>>(cs, cnts, lossp, widx, rankw, rsorted,
                                        out + O_NCS, wn, out + O_LOSS);
    k_esum2   <<<256, 256, 0, stream>>>(z, rsorted, widx, esum);
    k_embed   <<<256, 256, 0, stream>>>(ea, esum, out + O_NCS, wn,
                                        out + O_NEA, out + O_NEMB);
}